// Round 6
// baseline (8609.883 us; speedup 1.0000x reference)
//
#include <hip/hip_runtime.h>
#include <hip/hip_bf16.h>

// Decoder: T=50, B=64, S=400, D=E=H=A=512, POOL=2.
// R6: persistent cooperative kernel for the scan with custom relaxed-atomic
// barriers (agent-scope sc0sc1 data path for cross-phase data; read-only big
// streams stay L2-cached -- no cache invalidation, unlike grid.sync).

#define T_STEPS 50
#define BB 64
#define SS 400
#define NBLK 256
#define NTHR 512

// output offsets (floats)
#define O_GOUT 0
#define O_HID 819200
#define O_ATTN_LAST 851968
#define O_CTXF 877568
#define O_PG 910336
#define O_GATTN 913536
#define O_COVL 2193536
#define O_COVF 2196736

typedef __attribute__((ext_vector_type(4))) float f4;
typedef __attribute__((ext_vector_type(8))) short s8v;
typedef unsigned long long u64;

static __device__ __forceinline__ float bf2f(unsigned short u){
  unsigned v = ((unsigned)u) << 16; return __builtin_bit_cast(float, v);
}
static __device__ __forceinline__ unsigned short f2bf(float f){
  unsigned u = __builtin_bit_cast(unsigned, f);
  unsigned r = (u + 0x7FFFu + ((u >> 16) & 1u)) >> 16;
  return (unsigned short)r;
}
static __device__ __forceinline__ float sigmoidf_(float x){ return 1.f/(1.f+__expf(-x)); }
static __device__ __forceinline__ float tanhf_(float x){ float e=__expf(2.f*x); return 1.f - 2.f/(e+1.f); }

// coherent (agent-scope, L2-bypass) helpers
static __device__ __forceinline__ u64 ald64(const void* p){
  return __hip_atomic_load((const u64*)p, __ATOMIC_RELAXED, __HIP_MEMORY_SCOPE_AGENT);
}
static __device__ __forceinline__ void ast64(void* p, u64 v){
  __hip_atomic_store((u64*)p, v, __ATOMIC_RELAXED, __HIP_MEMORY_SCOPE_AGENT);
}
static __device__ __forceinline__ float ald32f(const void* p){
  unsigned u = __hip_atomic_load((const unsigned*)p, __ATOMIC_RELAXED, __HIP_MEMORY_SCOPE_AGENT);
  return __builtin_bit_cast(float, u);
}
static __device__ __forceinline__ void ast32f(void* p, float v){
  __hip_atomic_store((unsigned*)p, __builtin_bit_cast(unsigned, v),
                     __ATOMIC_RELAXED, __HIP_MEMORY_SCOPE_AGENT);
}

static __device__ __forceinline__ void gbar(unsigned* bar, int idx){
  asm volatile("s_waitcnt vmcnt(0)" ::: "memory");   // every wave drains its stores
  __syncthreads();
  if(threadIdx.x==0){
    __hip_atomic_fetch_add(&bar[idx], 1u, __ATOMIC_RELAXED, __HIP_MEMORY_SCOPE_AGENT);
    while(__hip_atomic_load(&bar[idx], __ATOMIC_RELAXED, __HIP_MEMORY_SCOPE_AGENT) < (unsigned)NBLK)
      __builtin_amdgcn_s_sleep(2);
    asm volatile("" ::: "memory");
  }
  __syncthreads();
}

// ---------------- converts ----------------
__global__ void conv_ctx(const float* __restrict__ ctx, unsigned short* __restrict__ out){
  int o = blockIdx.x*256 + threadIdx.x;           // [S][B][E] -> [B][S][E] bf16
  if(o >= SS*BB*512) return;
  int e = o & 511; int b = (o>>9)&63; int s = o>>15;
  out[((b*SS+s)<<9) + e] = f2bf(ctx[o]);
}
__global__ void conv_emb(const int* __restrict__ y, const float* __restrict__ embW,
                         unsigned short* __restrict__ embU){
  int o = blockIdx.x*256+threadIdx.x; if(o>=T_STEPS*BB*512) return;
  int d = o & 511; int i = o>>9;
  embU[o] = f2bf(embW[(long)y[i]*512 + d]);
}
__global__ void conv_wihd(const float* __restrict__ W_ih, unsigned short* __restrict__ out){
  int o = blockIdx.x*256+threadIdx.x; if(o>=1536*512) return;
  int j = o>>9; int d = o&511;
  out[o] = f2bf(W_ih[(long)j*1024 + d]);
}
__global__ void conv_preT(const float* __restrict__ W_pre, unsigned short* __restrict__ out){
  int o = blockIdx.x*256+threadIdx.x; if(o>=512*512) return;
  int a = o>>9; int e = o&511;
  out[o] = f2bf(W_pre[(long)e*512 + a]);
}
__global__ void conv_roT(const float* __restrict__ W_ro, unsigned short* __restrict__ out){
  int o = blockIdx.x*256+threadIdx.x; if(o>=512*2048) return;
  int n = o>>11; int k = o&2047;
  out[o] = f2bf(W_ro[(long)k*512 + n]);
}
// GRU weights fragment-ordered: rg = blk*24 + w*6 + g*2+op
__global__ void conv_wgru(const float* __restrict__ W_ih, const float* __restrict__ W_hh,
                          unsigned short* __restrict__ Wp){
  int o = blockIdx.x*256+threadIdx.x; if(o >= 192*8192) return;
  int rg = o >> 13; int rem = o & 8191;
  int ki = rem >> 9; int ln = (rem >> 3) & 63; int e = o & 7;
  int blk = rg/24; int r2 = rg%24; int w = r2/6; int r3 = r2%6; int g = r3>>1; int op = r3&1;
  int rl = ln & 15; int kk = ((ln>>4)<<3) + e;
  int d = blk*64 + w*16 + rl; int j = g*512 + d; int k = ki*32 + kk;
  float v = op ? W_hh[(long)j*512 + k] : W_ih[(long)j*1024 + 512 + k];
  Wp[o] = f2bf(v);
}
// W_q(h-part) packed: [blk 0..7][nrg 0..31][kf 0..1][ln][8]
__global__ void conv_wq3(const float* __restrict__ W_q, unsigned short* __restrict__ Wp){
  int o = blockIdx.x*256+threadIdx.x; if(o>=262144) return;
  int e = o&7; int ln=(o>>3)&63; int kf=(o>>9)&1; int nrg=(o>>10)&31; int blk=o>>15;
  int n = nrg*16 + (ln&15);
  int k = blk*64 + kf*32 + ((ln>>4)<<3) + e;
  Wp[o] = f2bf(W_q[(long)k*512 + n]);
}
__global__ void k_init2(const float* __restrict__ hidden, const float* __restrict__ init_att,
                        const float* __restrict__ gctx, const float* __restrict__ coverage,
                        unsigned short* __restrict__ hcoh, unsigned short* __restrict__ ctx_coh,
                        float* __restrict__ gctxT, float* __restrict__ covbuf,
                        unsigned* __restrict__ bar){
  int o = blockIdx.x*256+threadIdx.x;
  if(o < 32768){ hcoh[o] = f2bf(hidden[o]); }
  else if(o < 65536){ int p=o-32768; ctx_coh[p] = f2bf(init_att[p]); }
  else if(o < 98304){ int p=o-65536; int b=p>>9,e=p&511; gctxT[e*64+b]=gctx[p]; }
  else if(o < 123904){ int p=o-98304; covbuf[p]=coverage[p]; }
  else if(o < 124032){ bar[o-123904] = 0u; }
}

// ---------------- MFMA GEMM (precompute/post) ----------------
template<int OUT_BF16, int ACCUM>
__global__ __launch_bounds__(256) void mfma_gemm(
    const unsigned short* __restrict__ Abf, int lda,
    const unsigned short* __restrict__ Bbf, int ldb, int koff,
    void* __restrict__ Cp, int ldc, const float* __restrict__ bias, int K)
{
  __shared__ __align__(16) unsigned short Ash[128*40];
  __shared__ __align__(16) unsigned short Bsh[128*40];
  int m0 = blockIdx.x*128, n0 = blockIdx.y*128;
  int tid = threadIdx.x;
  int wid = tid>>6, lane = tid&63;
  int wm = wid>>1, wn = wid&1;
  int lr = lane&15, lg = lane>>4;
  f4 acc[4][4];
  #pragma unroll
  for(int i=0;i<4;i++)
    #pragma unroll
    for(int j=0;j<4;j++) acc[i][j]=(f4)0.f;

  for(int kt=0; kt<K; kt+=32){
    #pragma unroll
    for(int c=0;c<2;c++){
      int flat = tid*16 + c*8;
      int row = flat>>5, col = flat&31;
      const unsigned short* ga = Abf + (long)(m0+row)*lda + kt + col;
      *(uint4*)(&Ash[row*40+col]) = *(const uint4*)ga;
      const unsigned short* gb = Bbf + (long)(n0+row)*ldb + koff + kt + col;
      *(uint4*)(&Bsh[row*40+col]) = *(const uint4*)gb;
    }
    __syncthreads();
    s8v av[4], bv[4];
    #pragma unroll
    for(int mi=0;mi<4;mi++) av[mi] = *(const s8v*)(&Ash[(wm*64+mi*16+lr)*40 + lg*8]);
    #pragma unroll
    for(int ni=0;ni<4;ni++) bv[ni] = *(const s8v*)(&Bsh[(wn*64+ni*16+lr)*40 + lg*8]);
    #pragma unroll
    for(int mi=0;mi<4;mi++)
      #pragma unroll
      for(int ni=0;ni<4;ni++)
        acc[mi][ni] = __builtin_amdgcn_mfma_f32_16x16x32_bf16(av[mi], bv[ni], acc[mi][ni], 0,0,0);
    __syncthreads();
  }
  #pragma unroll
  for(int mi=0;mi<4;mi++)
    #pragma unroll
    for(int ni=0;ni<4;ni++){
      int gc = n0 + wn*64 + ni*16 + lr;
      #pragma unroll
      for(int r=0;r<4;r++){
        int gr = m0 + wm*64 + mi*16 + lg*4 + r;
        float v = acc[mi][ni][r];
        if(bias) v += bias[gc];
        if(OUT_BF16){
          ((unsigned short*)Cp)[(long)gr*ldc + gc] = f2bf(v);
        } else {
          float* C = (float*)Cp;
          if(ACCUM) v += C[(long)gr*ldc+gc];
          C[(long)gr*ldc+gc] = v;
        }
      }
    }
}

// ---------------- small fp32 GEMM (one-time) ----------------
__global__ __launch_bounds__(256) void small_gemm_kn(
  const float* __restrict__ AT, const float* __restrict__ W, int koff, int N,
  float* __restrict__ out)
{
  int tid = threadIdx.x;
  int b = tid&63; int nq = tid>>6;
  int n = __builtin_amdgcn_readfirstlane(blockIdx.x*4 + nq);
  float acc = 0.f;
  const float* wp = W + (long)koff*N + n;
  #pragma unroll 8
  for(int k=0;k<512;k++){
    acc = fmaf(AT[k*64+b], wp[(long)k*N], acc);
  }
  out[b*N+n] = acc;
}

// ---------------- persistent scan ----------------
__global__ __launch_bounds__(NTHR, 2) void k_scan2(
  const unsigned short* __restrict__ Wgru, const unsigned short* __restrict__ WqP,
  const unsigned short* __restrict__ pre, const unsigned short* __restrict__ ctxbf,
  unsigned short* __restrict__ ctxA, unsigned short* __restrict__ h0bf_all,
  unsigned short* ctx_coh, unsigned short* hcoh, float* covbuf,
  float* qpart, unsigned* bar,
  const float* __restrict__ gi_emb, const float* __restrict__ b_hh,
  const float* __restrict__ q_g, const float* __restrict__ Wv,
  const float* __restrict__ Wcov, const float* __restrict__ padm,
  const float* __restrict__ hidden, float* __restrict__ outp)
{
  __shared__ __align__(16) unsigned short Ash[64*256];   // 32KB (one op x K-half slice)
  __shared__ __align__(16) unsigned short HS[64*72];     // 9.2KB
  __shared__ float q_sh[512];
  __shared__ float wv_sh[512];
  __shared__ float wc_sh[512];
  __shared__ float covL[400];
  __shared__ float sm[400];
  __shared__ float red[512];
  __shared__ float pb[8][128];
  __shared__ unsigned short ctmp[128];

  const int blk = blockIdx.x;
  const int tid = threadIdx.x;
  const int w = tid>>6, lane = tid&63;
  const int lr = lane&15, lg = lane>>4;
  const int swz = (lr&7)<<4;
  char* ash_b = (char*)Ash;

  // P2 mapping (XCD-local redundancy: all 4 eq for a b land on one XCD)
  const int b2 = blk & 63;
  const int eq = blk >> 6;

  // P1: register-carried h (fp32), blocks 0..7, waves 0..3
  float h_reg[4][4];
  const int d_dim = blk*64 + w*16 + lr;
  if(blk<8 && w<4){
    #pragma unroll
    for(int mi=0;mi<4;mi++)
      #pragma unroll
      for(int r=0;r<4;r++) h_reg[mi][r] = hidden[(long)(mi*16+lg*4+r)*512 + d_dim];
  }

  #pragma unroll 1
  for(int t=0; t<T_STEPS; t++){
    unsigned short* hb_in  = hcoh + (t&1)*32768;
    unsigned short* hb_out = hcoh + ((t+1)&1)*32768;
    float* covr = covbuf + (t&1)*25600;
    float* covw = covbuf + ((t+1)&1)*25600;

    // ================= P1: GRU + q-partials (blocks 0..7) =================
    if(blk<8){
      f4 acc2[6][4];
      #pragma unroll
      for(int u=0;u<6;u++)
        #pragma unroll
        for(int mi=0;mi<4;mi++) acc2[u][mi]=(f4)0.f;
      const int rgbase = blk*24 + w*6;

      #pragma unroll
      for(int op=0; op<2; op++){
        const unsigned short* srcb = op ? hb_in : ctx_coh;
        #pragma unroll
        for(int kp=0; kp<2; kp++){
          for(int c=tid; c<4096; c+=NTHR){
            int row=c>>6, k8=c&63;
            u64 v = ald64(srcb + row*512 + kp*256 + k8*4);
            int dst = row*512 + ((((k8>>1)<<4) ^ ((row&7)<<4))) + (k8&1)*8;
            *(u64*)(ash_b + dst) = v;
          }
          __syncthreads();
          if(w<4){
            #pragma unroll 2
            for(int ktl=0; ktl<256; ktl+=32){
              s8v av[4];
              #pragma unroll
              for(int mi=0;mi<4;mi++)
                av[mi] = *(const s8v*)(ash_b + (mi*16+lr)*512 + ((ktl*2 + lg*16) ^ swz));
              int ki = kp*8 + (ktl>>5);
              #pragma unroll
              for(int g=0;g<3;g++){
                int u = g*2+op;
                s8v bv = *(const s8v*)(Wgru + (long)(rgbase+u)*8192 + ki*512 + lane*8);
                #pragma unroll
                for(int mi=0;mi<4;mi++)
                  acc2[u][mi] = __builtin_amdgcn_mfma_f32_16x16x32_bf16(av[mi], bv, acc2[u][mi], 0,0,0);
              }
            }
          }
          __syncthreads();
        }
      }
      if(w<4){
        float bhr=b_hh[d_dim], bhz=b_hh[512+d_dim], bhn=b_hh[1024+d_dim];
        #pragma unroll
        for(int mi=0;mi<4;mi++){
          #pragma unroll
          for(int r=0;r<4;r++){
            int b = mi*16 + lg*4 + r;
            const float* ge = gi_emb + (long)(t*64+b)*1536;
            float g0 = __builtin_nontemporal_load(ge + d_dim);
            float g1 = __builtin_nontemporal_load(ge + 512 + d_dim);
            float g2 = __builtin_nontemporal_load(ge + 1024 + d_dim);
            float rr = sigmoidf_(g0 + bhr + acc2[0][mi][r] + acc2[1][mi][r]);
            float zz = sigmoidf_(g1 + bhz + acc2[2][mi][r] + acc2[3][mi][r]);
            float nn = tanhf_(  g2       + acc2[4][mi][r] + rr*(acc2[5][mi][r] + bhn));
            float hv = (1.f-zz)*nn + zz*h_reg[mi][r];
            h_reg[mi][r]=hv;
            unsigned short hbv = f2bf(hv);
            h0bf_all[(long)(t*64+b)*512 + d_dim] = hbv;
            HS[b*72 + w*16 + lr] = hbv;
            if(t==T_STEPS-1) outp[O_HID + b*512 + d_dim] = hv;
          }
        }
      }
      __syncthreads();
      // repack h slice -> coherent buffer (u64)
      for(int c=tid; c<1024; c+=NTHR){
        int b=c>>4, d8=c&15;
        u64 v = *(const u64*)(HS + b*72 + d8*4);
        ast64(hb_out + b*512 + blk*64 + d8*4, v);
      }
      // q-partials (MFMA over this block's 64 k-dims)
      if(w<4){
        #pragma unroll
        for(int i=0;i<8;i++){
          f4 accq[4];
          #pragma unroll
          for(int mi=0;mi<4;mi++) accq[mi]=(f4)0.f;
          #pragma unroll
          for(int kf=0;kf<2;kf++){
            s8v bv = *(const s8v*)(WqP + ((((long)blk*32 + (w*8+i))*2 + kf)*64 + lane)*8);
            #pragma unroll
            for(int mi=0;mi<4;mi++){
              s8v av = *(const s8v*)(HS + (mi*16+lr)*72 + kf*32 + lg*8);
              accq[mi] = __builtin_amdgcn_mfma_f32_16x16x32_bf16(av, bv, accq[mi], 0,0,0);
            }
          }
          int n = w*128 + i*16 + lr;
          #pragma unroll
          for(int mi=0;mi<4;mi++)
            #pragma unroll
            for(int r=0;r<4;r++)
              ast32f(qpart + (long)blk*32768 + (long)(mi*16+lg*4+r)*512 + n, accq[mi][r]);
        }
      }
    }
    gbar(bar, 2*t);

    // ================= P2: attention (all 256 blocks) =================
    {
      // q reduce + weights to LDS
      float qv = q_g[b2*512 + tid];
      #pragma unroll
      for(int p=0;p<8;p++) qv += ald32f(qpart + ((long)p<<15) + b2*512 + tid);
      q_sh[tid]=qv;
      wv_sh[tid]=Wv[tid]; wc_sh[tid]=Wcov[tid];
      if(tid<200){
        u64 cv2 = ald64(covr + b2*400 + tid*2);
        covL[tid*2]   = __builtin_bit_cast(float,(unsigned)(cv2 & 0xffffffffu));
        covL[tid*2+1] = __builtin_bit_cast(float,(unsigned)(cv2 >> 32));
      }
      __syncthreads();
      // energy (redundant per eq; all 400 s)
      for(int u=tid; u<800; u+=NTHR){
        int s=u>>1, half=u&1;
        const unsigned short* rp = pre + (((long)(b2*400+s))<<9) + half*256;
        float cv = covL[s];
        float part=0.f;
        #pragma unroll 4
        for(int j=0;j<32;j++){
          uint4 uv = *(const uint4*)(rp + j*8);
          const unsigned* uu = (const unsigned*)&uv;
          #pragma unroll
          for(int q4=0;q4<4;q4++){
            int a = half*256 + j*8 + q4*2;
            part += wv_sh[a]  * tanhf_(bf2f((unsigned short)(uu[q4]&0xffffu)) + q_sh[a]   + cv*wc_sh[a]);
            part += wv_sh[a+1]* tanhf_(bf2f((unsigned short)(uu[q4]>>16))     + q_sh[a+1] + cv*wc_sh[a+1]);
          }
        }
        part += __shfl_xor(part, 1, 64);
        if(half==0) sm[s] = (padm[b2*400+s]>0.5f) ? -1e18f : part;
      }
      __syncthreads();
      // softmax over sm[400]
      red[tid] = (tid<400) ? sm[tid] : -3e38f;
      __syncthreads();
      for(int o=256;o;o>>=1){ if(tid<o) red[tid]=fmaxf(red[tid],red[tid+o]); __syncthreads(); }
      float mx = red[0]; __syncthreads();
      float pv = 0.f;
      if(tid<400){ pv = __expf(sm[tid]-mx); }
      red[tid]=pv; __syncthreads();
      for(int o=256;o;o>>=1){ if(tid<o) red[tid]+=red[tid+o]; __syncthreads(); }
      float inv = 1.f/red[0]; __syncthreads();
      if(tid<400) sm[tid] = pv*inv;
      __syncthreads();
      // coverage / covl / gattn (eq==0 stores; all compute)
      float clp = 0.f;
      if(tid<400){
        float a = sm[tid];
        float c = covL[tid];
        clp = fminf(a,c);
        if(eq==0){
          float nc = c + a;
          outp[O_GATTN + (long)t*25600 + b2*400 + tid] = a;
          ast32f(covw + b2*400 + tid, nc);
          if(t==T_STEPS-1){
            outp[O_ATTN_LAST + b2*400 + tid] = a;
            outp[O_COVF + b2*400 + tid] = nc;
          }
        }
      }
      red[tid]=clp; __syncthreads();
      for(int o=256;o;o>>=1){ if(tid<o) red[tid]+=red[tid+o]; __syncthreads(); }
      if(eq==0 && tid==0) outp[O_COVL + t*64 + b2] = red[0];
      __syncthreads();
      // context slice [eq*128, eq*128+128)
      float a0=0.f, a1=0.f;
      for(int s=w; s<400; s+=8){
        float av = sm[s];
        unsigned uv = *(const unsigned*)(ctxbf + (((long)(b2*400+s))<<9) + eq*128 + lane*2);
        a0 = fmaf(av, bf2f((unsigned short)(uv&0xffffu)), a0);
        a1 = fmaf(av, bf2f((unsigned short)(uv>>16)),     a1);
      }
      pb[w][lane*2]=a0; pb[w][lane*2+1]=a1;
      __syncthreads();
      if(tid<128){
        float v = pb[0][tid]+pb[1][tid]+pb[2][tid]+pb[3][tid]
                 +pb[4][tid]+pb[5][tid]+pb[6][tid]+pb[7][tid];
        int d = eq*128 + tid;
        ctmp[tid] = f2bf(v);
        ctxA[(long)(t*64+b2)*512 + d] = f2bf(v);
        if(t==T_STEPS-1) outp[O_CTXF + b2*512 + d] = v;
      }
      __syncthreads();
      if(tid<32){
        u64 v = *(const u64*)(ctmp + tid*4);
        ast64(ctx_coh + b2*512 + eq*128 + tid*4, v);
      }
    }
    gbar(bar, 2*t+1);
  }
}

// ---------------- post-pass ----------------
__global__ __launch_bounds__(256) void k_pgen(
  const unsigned short* __restrict__ embU, const unsigned short* __restrict__ h0bf,
  const unsigned short* __restrict__ ctxA, const float* __restrict__ Wpg,
  const float* __restrict__ bpg, float* __restrict__ outp)
{
  int wid = threadIdx.x>>6, lane=threadIdx.x&63;
  int m = blockIdx.x*4 + wid;
  float acc=0.f;
  #pragma unroll
  for(int i=0;i<8;i++){
    int k = i*64+lane;
    acc = fmaf(bf2f(ctxA[(long)m*512+k]), Wpg[k], acc);
    acc = fmaf(bf2f(h0bf[(long)m*512+k]), Wpg[512+k], acc);
    acc = fmaf(bf2f(embU[(long)m*512+k]), Wpg[1024+k], acc);
  }
  #pragma unroll
  for(int off=32; off; off>>=1) acc += __shfl_xor(acc, off, 64);
  if(lane==0) outp[O_PG + m] = sigmoidf_(acc + bpg[0]);
}

__global__ void k_maxout(const float* __restrict__ RO, const float* __restrict__ ro_g,
                         float* __restrict__ outp){
  int o = blockIdx.x*256+threadIdx.x; if(o>=819200) return;
  int h = o & 255; int m = o>>8; int b = m & 63;
  float v0 = RO[(long)m*512 + 2*h]   + ro_g[b*512 + 2*h];
  float v1 = RO[(long)m*512 + 2*h+1] + ro_g[b*512 + 2*h+1];
  outp[O_GOUT + o] = fmaxf(v0,v1);
}

extern "C" void kernel_launch(void* const* d_in, const int* in_sizes, int n_in,
                              void* d_out, int out_size, void* d_ws, size_t ws_size,
                              hipStream_t stream)
{
  (void)in_sizes; (void)n_in; (void)out_size; (void)ws_size;
  const int*   y       = (const int*)d_in[0];
  const float* hidden  = (const float*)d_in[1];
  const float* context = (const float*)d_in[2];
  const float* padm    = (const float*)d_in[3];
  const float* init_att= (const float*)d_in[4];
  const float* coverage= (const float*)d_in[5];
  const float* gctx    = (const float*)d_in[6];
  const float* embW    = (const float*)d_in[7];
  const float* W_ih    = (const float*)d_in[8];
  const float* W_hh    = (const float*)d_in[9];
  const float* b_ih    = (const float*)d_in[10];
  const float* b_hh    = (const float*)d_in[11];
  const float* W_pre   = (const float*)d_in[12];
  const float* b_pre   = (const float*)d_in[13];
  const float* W_q     = (const float*)d_in[14];
  const float* W_v     = (const float*)d_in[15];
  const float* W_cov   = (const float*)d_in[16];
  const float* W_pg    = (const float*)d_in[17];
  const float* b_pg    = (const float*)d_in[18];
  const float* W_ro    = (const float*)d_in[19];
  const float* b_ro    = (const float*)d_in[20];
  float* out = (float*)d_out;

  char* wsb = (char*)d_ws;
  size_t off = 0;
  auto alloc = [&](size_t bytes)->char*{ char* p = wsb+off; off += (bytes+255)&~255UL; return p; };
  unsigned short* pre    = (unsigned short*)alloc(25600UL*512*2);
  unsigned short* ctxbf  = (unsigned short*)alloc(13107200UL*2);
  unsigned short* embU   = (unsigned short*)alloc(3200UL*512*2);
  unsigned short* wihbf  = (unsigned short*)alloc(1536UL*512*2);
  unsigned short* wpreT  = (unsigned short*)alloc(512UL*512*2);
  unsigned short* wroT   = (unsigned short*)alloc(512UL*2048*2);
  unsigned short* Wgru   = (unsigned short*)alloc(192UL*8192*2);
  unsigned short* WqP    = (unsigned short*)alloc(262144UL*2);
  float* gi_emb = (float*)alloc(3200UL*1536*4);
  float* RO     = (float*)alloc(3200UL*512*4);
  float* q_g    = (float*)alloc(64UL*512*4);
  float* ro_g   = (float*)alloc(64UL*512*4);
  float* gctxT  = (float*)alloc(512UL*64*4);
  unsigned short* h0bf = (unsigned short*)alloc(3200UL*512*2);
  unsigned short* ctxA = (unsigned short*)alloc(3200UL*512*2);
  unsigned short* hcoh = (unsigned short*)alloc(2UL*32768*2);
  unsigned short* ctxcoh=(unsigned short*)alloc(32768UL*2);
  float* covbuf = (float*)alloc(2UL*25600*4);
  float* qpart  = (float*)alloc(8UL*64*512*4);
  unsigned* bar = (unsigned*)alloc(128UL*4);

  // converts + init
  conv_ctx <<<dim3(51200),dim3(256),0,stream>>>(context, ctxbf);
  conv_emb <<<dim3(6400), dim3(256),0,stream>>>(y, embW, embU);
  conv_wihd<<<dim3(3072), dim3(256),0,stream>>>(W_ih, wihbf);
  conv_preT<<<dim3(1024), dim3(256),0,stream>>>(W_pre, wpreT);
  conv_roT <<<dim3(4096), dim3(256),0,stream>>>(W_ro, wroT);
  conv_wgru<<<dim3(6144), dim3(256),0,stream>>>(W_ih, W_hh, Wgru);
  conv_wq3 <<<dim3(1024), dim3(256),0,stream>>>(W_q, WqP);
  k_init2  <<<dim3(485),  dim3(256),0,stream>>>(hidden, init_att, gctx, coverage,
                                                hcoh, ctxcoh, gctxT, covbuf, bar);

  // precompute GEMMs
  mfma_gemm<1,0><<<dim3(200,4),dim3(256),0,stream>>>(ctxbf,512, wpreT,512,0,  pre,   512, b_pre, 512);
  mfma_gemm<0,0><<<dim3(25,12),dim3(256),0,stream>>>(embU, 512, wihbf,512,0,  gi_emb,1536,b_ih, 512);
  mfma_gemm<0,0><<<dim3(25,4), dim3(256),0,stream>>>(embU, 512, wroT,2048,0,  RO,    512, b_ro, 512);
  small_gemm_kn<<<dim3(128),dim3(256),0,stream>>>(gctxT, W_q, 512, 512, q_g);
  small_gemm_kn<<<dim3(128),dim3(256),0,stream>>>(gctxT, W_ro,1536, 512, ro_g);

  // persistent scan (cooperative)
  {
    const unsigned short *wgru_c=Wgru, *wqp_c=WqP, *pre_c=pre, *ctxbf_c=ctxbf;
    unsigned short *ctxA_p=ctxA, *h0bf_p=h0bf, *ctxcoh_p=ctxcoh, *hcoh_p=hcoh;
    float *covbuf_p=covbuf, *qpart_p=qpart;
    unsigned* bar_p=bar;
    const float *gi_c=gi_emb, *bhh_c=b_hh, *qg_c=q_g, *wv_c=W_v, *wcov_c=W_cov,
                *padm_c=padm, *hid_c=hidden;
    float* out_p=out;
    void* args[] = {
      (void*)&wgru_c, (void*)&wqp_c, (void*)&pre_c, (void*)&ctxbf_c,
      (void*)&ctxA_p, (void*)&h0bf_p, (void*)&ctxcoh_p, (void*)&hcoh_p,
      (void*)&covbuf_p, (void*)&qpart_p, (void*)&bar_p,
      (void*)&gi_c, (void*)&bhh_c, (void*)&qg_c, (void*)&wv_c, (void*)&wcov_c,
      (void*)&padm_c, (void*)&hid_c, (void*)&out_p
    };
    hipLaunchCooperativeKernel(reinterpret_cast<void*>(k_scan2),
                               dim3(NBLK), dim3(NTHR), args, 0, stream);
  }

  // post-pass
  mfma_gemm<0,1><<<dim3(25,4),dim3(256),0,stream>>>(h0bf,512, wroT,2048,512,  RO,512, nullptr, 512);
  mfma_gemm<0,1><<<dim3(25,4),dim3(256),0,stream>>>(ctxA,512, wroT,2048,1024, RO,512, nullptr, 512);
  k_pgen  <<<dim3(800),dim3(256),0,stream>>>(embU, h0bf, ctxA, W_pg, b_pg, out);
  k_maxout<<<dim3(3200),dim3(256),0,stream>>>(RO, ro_g, out);
}

// Round 7
// 3010.901 us; speedup vs baseline: 2.8596x; 2.8596x over previous
//
#include <hip/hip_runtime.h>
#include <hip/hip_bf16.h>

// Decoder: T=50, B=64, S=400, D=E=H=A=512, POOL=2.
// R7: multi-kernel, 2 kernels/step via max-free softmax:
//   k_gru3 (grid 72): blocks 0-7 MFMA GRU(t)+q-partials (staging normalizes
//   ctx(t-1) from unnormalized partials); blocks 8-71 finalize attention(t-1)
//   (attn=p/S, gattn/cov/covl).
//   k_energy2 (grid 4x64): energy -> p=exp(e) (no max; |e|<~25 bounded),
//   partial sums S_part, unnormalized context partials ctxP.
// Fused converts, fused 3-source RO GEMM (K=1536), fused pgen+maxout.

#define T_STEPS 50
#define BB 64
#define SS 400

// output offsets (floats)
#define O_GOUT 0
#define O_HID 819200
#define O_ATTN_LAST 851968
#define O_CTXF 877568
#define O_PG 910336
#define O_GATTN 913536
#define O_COVL 2193536
#define O_COVF 2196736

typedef __attribute__((ext_vector_type(4))) float f4;
typedef __attribute__((ext_vector_type(8))) short s8v;
typedef __attribute__((ext_vector_type(4))) unsigned u4;

static __device__ __forceinline__ float bf2f(unsigned short u){
  unsigned v = ((unsigned)u) << 16; return __builtin_bit_cast(float, v);
}
static __device__ __forceinline__ unsigned short f2bf(float f){
  unsigned u = __builtin_bit_cast(unsigned, f);
  unsigned r = (u + 0x7FFFu + ((u >> 16) & 1u)) >> 16;
  return (unsigned short)r;
}
static __device__ __forceinline__ float sigmoidf_(float x){ return 1.f/(1.f+__expf(-x)); }
static __device__ __forceinline__ float tanhf_(float x){ float e=__expf(2.f*x); return 1.f - 2.f/(e+1.f); }
static __device__ __forceinline__ u4 ntld(const unsigned short* p){
  return __builtin_nontemporal_load((const u4*)p);
}

// ---------------- converts ----------------
__global__ void conv_ctx(const float* __restrict__ ctx, unsigned short* __restrict__ out){
  int o = blockIdx.x*256 + threadIdx.x;           // [S][B][E] -> [B][S][E] bf16
  if(o >= SS*BB*512) return;
  int e = o & 511; int b = (o>>9)&63; int s = o>>15;
  out[((b*SS+s)<<9) + e] = f2bf(ctx[o]);
}
__global__ void conv_emb(const int* __restrict__ y, const float* __restrict__ embW,
                         unsigned short* __restrict__ embU){
  int o = blockIdx.x*256+threadIdx.x; if(o>=T_STEPS*BB*512) return;
  int d = o & 511; int i = o>>9;
  embU[o] = f2bf(embW[(long)y[i]*512 + d]);
}
// fused small converts + init:
// seg0 wihd [0,786432) seg1 preT [786432,1048576) seg2 roT [1048576,2097152)
// seg3 wgru [2097152,3670016) seg4 wq3 [3670016,3932160) seg5 init [3932160,4056064)
__global__ void conv_rest(const float* __restrict__ W_ih, const float* __restrict__ W_hh,
                          const float* __restrict__ W_pre, const float* __restrict__ W_ro,
                          const float* __restrict__ W_q,
                          const float* __restrict__ hidden, const float* __restrict__ init_att,
                          const float* __restrict__ gctx, const float* __restrict__ coverage,
                          unsigned short* __restrict__ wihbf, unsigned short* __restrict__ wpreT,
                          unsigned short* __restrict__ wroT, unsigned short* __restrict__ Wgru,
                          unsigned short* __restrict__ WqP,
                          float* __restrict__ hrow0, unsigned short* __restrict__ h0bf_init,
                          unsigned short* __restrict__ ctx0bf, float* __restrict__ gctxT,
                          float* __restrict__ cov){
  int o = blockIdx.x*256+threadIdx.x;
  if(o < 786432){
    int j = o>>9; int d = o&511;
    wihbf[o] = f2bf(W_ih[(long)j*1024 + d]);
  } else if(o < 1048576){
    int p = o - 786432;
    int a = p>>9; int e = p&511;
    wpreT[p] = f2bf(W_pre[(long)e*512 + a]);
  } else if(o < 2097152){
    int p = o - 1048576;
    int n = p>>11; int k = p&2047;
    wroT[p] = f2bf(W_ro[(long)k*512 + n]);
  } else if(o < 3670016){
    int p = o - 2097152;
    int rg = p >> 13; int rem = p & 8191;
    int ki = rem >> 9; int ln = (rem >> 3) & 63; int e = p & 7;
    int blk = rg/24; int r2 = rg%24; int w = r2/6; int r3 = r2%6; int g = r3>>1; int op = r3&1;
    int rl = ln & 15; int kk = ((ln>>4)<<3) + e;
    int d = blk*64 + w*16 + rl; int j = g*512 + d; int k = ki*32 + kk;
    float v = op ? W_hh[(long)j*512 + k] : W_ih[(long)j*1024 + 512 + k];
    Wgru[p] = f2bf(v);
  } else if(o < 3932160){
    int p = o - 3670016;
    int e = p&7; int ln=(p>>3)&63; int kf=(p>>9)&1; int nrg=(p>>10)&31; int blk=p>>15;
    int n = nrg*16 + (ln&15);
    int k = blk*64 + kf*32 + ((ln>>4)<<3) + e;
    WqP[p] = f2bf(W_q[(long)k*512 + n]);
  } else if(o < 4056064){
    int p = o - 3932160;
    if(p < 32768){ float v = hidden[p]; hrow0[p] = v; h0bf_init[p] = f2bf(v); }
    else if(p < 65536){ int q=p-32768; ctx0bf[q] = f2bf(init_att[q]); }
    else if(p < 98304){ int q=p-65536; int b=q>>9,e=q&511; gctxT[e*64+b]=gctx[q]; }
    else { int q=p-98304; cov[q]=coverage[q]; }
  }
}

// ---------------- MFMA GEMM (precompute) ----------------
template<int OUT_BF16>
__global__ __launch_bounds__(256) void mfma_gemm(
    const unsigned short* __restrict__ Abf, int lda,
    const unsigned short* __restrict__ Bbf, int ldb,
    void* __restrict__ Cp, int ldc, const float* __restrict__ bias, int K)
{
  __shared__ __align__(16) unsigned short Ash[128*40];
  __shared__ __align__(16) unsigned short Bsh[128*40];
  int m0 = blockIdx.x*128, n0 = blockIdx.y*128;
  int tid = threadIdx.x;
  int wid = tid>>6, lane = tid&63;
  int wm = wid>>1, wn = wid&1;
  int lr = lane&15, lg = lane>>4;
  f4 acc[4][4];
  #pragma unroll
  for(int i=0;i<4;i++)
    #pragma unroll
    for(int j=0;j<4;j++) acc[i][j]=(f4)0.f;

  for(int kt=0; kt<K; kt+=32){
    #pragma unroll
    for(int c=0;c<2;c++){
      int flat = tid*16 + c*8;
      int row = flat>>5, col = flat&31;
      const unsigned short* ga = Abf + (long)(m0+row)*lda + kt + col;
      *(uint4*)(&Ash[row*40+col]) = *(const uint4*)ga;
      const unsigned short* gb = Bbf + (long)(n0+row)*ldb + kt + col;
      *(uint4*)(&Bsh[row*40+col]) = *(const uint4*)gb;
    }
    __syncthreads();
    s8v av[4], bv[4];
    #pragma unroll
    for(int mi=0;mi<4;mi++) av[mi] = *(const s8v*)(&Ash[(wm*64+mi*16+lr)*40 + lg*8]);
    #pragma unroll
    for(int ni=0;ni<4;ni++) bv[ni] = *(const s8v*)(&Bsh[(wn*64+ni*16+lr)*40 + lg*8]);
    #pragma unroll
    for(int mi=0;mi<4;mi++)
      #pragma unroll
      for(int ni=0;ni<4;ni++)
        acc[mi][ni] = __builtin_amdgcn_mfma_f32_16x16x32_bf16(av[mi], bv[ni], acc[mi][ni], 0,0,0);
    __syncthreads();
  }
  #pragma unroll
  for(int mi=0;mi<4;mi++)
    #pragma unroll
    for(int ni=0;ni<4;ni++){
      int gc = n0 + wn*64 + ni*16 + lr;
      #pragma unroll
      for(int r=0;r<4;r++){
        int gr = m0 + wm*64 + mi*16 + lg*4 + r;
        float v = acc[mi][ni][r];
        if(bias) v += bias[gc];
        if(OUT_BF16) ((unsigned short*)Cp)[(long)gr*ldc + gc] = f2bf(v);
        else         ((float*)Cp)[(long)gr*ldc + gc] = v;
      }
    }
}

// ---------------- 3-source RO GEMM: RO = [emb|h0|ctx] @ W_ro[0:1536] + b_ro ----------------
__global__ __launch_bounds__(256) void mfma_gemm_ro(
    const unsigned short* __restrict__ embU, const unsigned short* __restrict__ h0bf,
    const unsigned short* __restrict__ ctxA, const unsigned short* __restrict__ wroT,
    float* __restrict__ RO, const float* __restrict__ bias)
{
  __shared__ __align__(16) unsigned short Ash[128*40];
  __shared__ __align__(16) unsigned short Bsh[128*40];
  int m0 = blockIdx.x*128, n0 = blockIdx.y*128;
  int tid = threadIdx.x;
  int wid = tid>>6, lane = tid&63;
  int wm = wid>>1, wn = wid&1;
  int lr = lane&15, lg = lane>>4;
  f4 acc[4][4];
  #pragma unroll
  for(int i=0;i<4;i++)
    #pragma unroll
    for(int j=0;j<4;j++) acc[i][j]=(f4)0.f;

  for(int kt=0; kt<1536; kt+=32){
    const unsigned short* src = (kt<512) ? embU : (kt<1024) ? h0bf : ctxA;
    int klocal = kt & 511;
    #pragma unroll
    for(int c=0;c<2;c++){
      int flat = tid*16 + c*8;
      int row = flat>>5, col = flat&31;
      *(uint4*)(&Ash[row*40+col]) = *(const uint4*)(src + (long)(m0+row)*512 + klocal + col);
      *(uint4*)(&Bsh[row*40+col]) = *(const uint4*)(wroT + (long)(n0+row)*2048 + kt + col);
    }
    __syncthreads();
    s8v av[4], bv[4];
    #pragma unroll
    for(int mi=0;mi<4;mi++) av[mi] = *(const s8v*)(&Ash[(wm*64+mi*16+lr)*40 + lg*8]);
    #pragma unroll
    for(int ni=0;ni<4;ni++) bv[ni] = *(const s8v*)(&Bsh[(wn*64+ni*16+lr)*40 + lg*8]);
    #pragma unroll
    for(int mi=0;mi<4;mi++)
      #pragma unroll
      for(int ni=0;ni<4;ni++)
        acc[mi][ni] = __builtin_amdgcn_mfma_f32_16x16x32_bf16(av[mi], bv[ni], acc[mi][ni], 0,0,0);
    __syncthreads();
  }
  #pragma unroll
  for(int mi=0;mi<4;mi++)
    #pragma unroll
    for(int ni=0;ni<4;ni++){
      int gc = n0 + wn*64 + ni*16 + lr;
      #pragma unroll
      for(int r=0;r<4;r++){
        int gr = m0 + wm*64 + mi*16 + lg*4 + r;
        RO[(long)gr*512 + gc] = acc[mi][ni][r] + bias[gc];
      }
    }
}

// ---------------- fused small fp32 GEMMs: q_g and ro_g ----------------
__global__ __launch_bounds__(256) void small2(
  const float* __restrict__ AT, const float* __restrict__ W_q, const float* __restrict__ W_ro,
  float* __restrict__ q_g, float* __restrict__ ro_g)
{
  int blk = blockIdx.x;
  int half = blk>>7; int nblk = blk&127;
  int tid = threadIdx.x;
  int b = tid&63; int nq = tid>>6;
  int n = __builtin_amdgcn_readfirstlane(nblk*4 + nq);
  const float* W = half ? W_ro : W_q;
  int koff = half ? 1536 : 512;
  float acc = 0.f;
  const float* wp = W + (long)koff*512 + n;
  #pragma unroll 8
  for(int k=0;k<512;k++){
    acc = fmaf(AT[k*64+b], wp[(long)k*512], acc);
  }
  (half ? ro_g : q_g)[b*512+n] = acc;
}

// ---------------- k_gru3: finalize(t-1) + MFMA GRU(t) + q-partials ----------------
__global__ __launch_bounds__(256) void k_gru3(
  const unsigned short* __restrict__ ctx0bf, const float* __restrict__ ctxP,
  const float* __restrict__ S_part, const float* __restrict__ P_exp,
  const unsigned short* __restrict__ hprevbf,
  const float* __restrict__ hrow_in, float* __restrict__ hrow_out,
  const unsigned short* __restrict__ Wp, const unsigned short* __restrict__ WqP,
  const float* __restrict__ gi_emb, const float* __restrict__ b_hh,
  unsigned short* __restrict__ h0bf_all, float* __restrict__ qpart,
  float* __restrict__ cov, unsigned short* __restrict__ ctxA,
  float* __restrict__ outp, int t)
{
  __shared__ __align__(16) unsigned short Ash[2*64*256];   // 64KB
  __shared__ __align__(16) unsigned short HS[64*72];
  __shared__ float invS[64];
  __shared__ float red[256];
  int blk = blockIdx.x;
  int tid = threadIdx.x;
  int w = tid>>6, lane = tid&63;
  int lr = lane&15, lg = lane>>4;

  if(blk >= 8){
    // -------- finalize attention of step t-1 for b = blk-8 --------
    if(t==0) return;
    int b = blk-8; int tb = t-1;
    float S = S_part[b*4]+S_part[b*4+1]+S_part[b*4+2]+S_part[b*4+3];
    float inv = 1.f/S;
    float clp;
    {
      float p = P_exp[b*400+tid];
      float attn = p*inv;
      float co = cov[b*400+tid];
      clp = fminf(attn, co);
      cov[b*400+tid] = co+attn;
      outp[O_GATTN + (long)tb*25600 + b*400 + tid] = attn;
    }
    if(tid<144){
      int i = 256+tid;
      float p = P_exp[b*400+i];
      float attn = p*inv;
      float co = cov[b*400+i];
      clp += fminf(attn, co);
      cov[b*400+i] = co+attn;
      outp[O_GATTN + (long)tb*25600 + b*400 + i] = attn;
    }
    red[tid]=clp; __syncthreads();
    for(int o=128;o;o>>=1){ if(tid<o) red[tid]+=red[tid+o]; __syncthreads(); }
    if(tid==0) outp[O_COVL + tb*64 + b] = red[0];
    return;
  }

  // -------- GRU blocks 0..7 --------
  int swz = (lr&7)<<4;
  int rgbase = blk*24 + w*6;
  if(t>0 && tid<64){
    float S = S_part[tid*4]+S_part[tid*4+1]+S_part[tid*4+2]+S_part[tid*4+3];
    invS[tid] = 1.f/S;
  }
  __syncthreads();

  f4 acc2[6][4];
  #pragma unroll
  for(int u=0;u<6;u++)
    #pragma unroll
    for(int mi=0;mi<4;mi++) acc2[u][mi]=(f4)0.f;

  for(int kp=0; kp<2; kp++){
    for(int c = tid; c < 4096; c += 256){
      int op = c>>11; int row = (c>>5)&63; int kc = c&31;
      int e0 = kp*256 + kc*8;
      u4 v;
      if(op){
        v = *(const u4*)(hprevbf + row*512 + e0);
      } else if(t>0){
        const float* cp = ctxP + (long)row*2048 + e0;
        float sc = invS[row];
        f4 a0 = *(const f4*)(cp);
        f4 a1 = *(const f4*)(cp+512);
        f4 a2 = *(const f4*)(cp+1024);
        f4 a3 = *(const f4*)(cp+1536);
        f4 b0 = *(const f4*)(cp+4);
        f4 b1 = *(const f4*)(cp+516);
        f4 b2 = *(const f4*)(cp+1028);
        f4 b3 = *(const f4*)(cp+1540);
        f4 s0 = (a0+a1+a2+a3)*sc;
        f4 s1 = (b0+b1+b2+b3)*sc;
        v.x = (unsigned)f2bf(s0.x) | ((unsigned)f2bf(s0.y)<<16);
        v.y = (unsigned)f2bf(s0.z) | ((unsigned)f2bf(s0.w)<<16);
        v.z = (unsigned)f2bf(s1.x) | ((unsigned)f2bf(s1.y)<<16);
        v.w = (unsigned)f2bf(s1.z) | ((unsigned)f2bf(s1.w)<<16);
        if(blk == (row>>3))
          *(u4*)(ctxA + ((long)((t-1)*64+row))*512 + e0) = v;
      } else {
        v = *(const u4*)(ctx0bf + row*512 + e0);
      }
      int dst = op*32768 + row*512 + ((kc*16) ^ ((row&7)<<4));
      *(u4*)((char*)Ash + dst) = v;
    }
    __syncthreads();
    #pragma unroll 2
    for(int ktl=0; ktl<256; ktl+=32){
      s8v av[2][4];
      #pragma unroll
      for(int op=0;op<2;op++)
        #pragma unroll
        for(int mi=0;mi<4;mi++)
          av[op][mi] = *(const s8v*)((const char*)Ash + op*32768 + (mi*16+lr)*512 + ((ktl*2 + lg*16) ^ swz));
      int ki = kp*8 + (ktl>>5);
      const unsigned short* wb = Wp + (long)rgbase*8192 + ki*512 + lane*8;
      #pragma unroll
      for(int u=0;u<6;u++){
        s8v bv = *(const s8v*)(wb + (long)u*8192);
        #pragma unroll
        for(int mi=0;mi<4;mi++)
          acc2[u][mi] = __builtin_amdgcn_mfma_f32_16x16x32_bf16(av[u&1][mi], bv, acc2[u][mi], 0,0,0);
      }
    }
    __syncthreads();
  }

  int d = blk*64 + w*16 + lr;
  float bhr = b_hh[d], bhz = b_hh[512+d], bhn = b_hh[1024+d];
  #pragma unroll
  for(int mi=0;mi<4;mi++){
    #pragma unroll
    for(int r=0;r<4;r++){
      int b = mi*16 + lg*4 + r;
      const float* ge = gi_emb + (long)(t*64+b)*1536;
      float g0 = __builtin_nontemporal_load(ge + d);
      float g1 = __builtin_nontemporal_load(ge + 512 + d);
      float g2 = __builtin_nontemporal_load(ge + 1024 + d);
      float rr = sigmoidf_(g0 + bhr + acc2[0][mi][r] + acc2[1][mi][r]);
      float zz = sigmoidf_(g1 + bhz + acc2[2][mi][r] + acc2[3][mi][r]);
      float nn = tanhf_(  g2       + acc2[4][mi][r] + rr*(acc2[5][mi][r] + bhn));
      float hp = hrow_in[b*512 + d];
      float hv = (1.f-zz)*nn + zz*hp;
      hrow_out[b*512+d] = hv;
      unsigned short hb = f2bf(hv);
      h0bf_all[(long)(t*64+b)*512 + d] = hb;
      HS[b*72 + w*16 + lr] = hb;
      if(t==T_STEPS-1) outp[O_HID + b*512 + d] = hv;
    }
  }
  __syncthreads();
  // q-partials over this block's 64 k-dims
  #pragma unroll
  for(int i=0;i<8;i++){
    f4 accq[4];
    #pragma unroll
    for(int mi=0;mi<4;mi++) accq[mi]=(f4)0.f;
    #pragma unroll
    for(int kf=0;kf<2;kf++){
      s8v bv = *(const s8v*)(WqP + ((((long)blk*32 + (w*8+i))*2 + kf)*64 + lane)*8);
      #pragma unroll
      for(int mi=0;mi<4;mi++){
        s8v av = *(const s8v*)(HS + (mi*16+lr)*72 + kf*32 + lg*8);
        accq[mi] = __builtin_amdgcn_mfma_f32_16x16x32_bf16(av, bv, accq[mi], 0,0,0);
      }
    }
    int n = w*128 + i*16 + lr;
    #pragma unroll
    for(int mi=0;mi<4;mi++)
      #pragma unroll
      for(int r=0;r<4;r++)
        qpart[(long)blk*32768 + (long)(mi*16+lg*4+r)*512 + n] = accq[mi][r];
  }
}

// ---------------- k_energy2: energy -> exp -> S_part + unnormalized ctx partials ----------------
__global__ __launch_bounds__(512) void k_energy2(
  const unsigned short* __restrict__ pre, const float* __restrict__ qpart,
  const float* __restrict__ q_g, const float* __restrict__ cov,
  const float* __restrict__ Wv, const float* __restrict__ Wcov,
  const float* __restrict__ padm, const unsigned short* __restrict__ ctxbf,
  float* __restrict__ P_exp, float* __restrict__ S_part, float* __restrict__ ctxP)
{
  __shared__ float q_sh[512], wv_sh[512], wc_sh[512];
  __shared__ float covL[104], padL[104], pL[104];
  __shared__ float pb[8][512];
  __shared__ float red2[8];
  int cq = blockIdx.x, b = blockIdx.y; int c0 = cq*100;
  int tid = threadIdx.x, w = tid>>6, lane = tid&63;
  {
    float acc = q_g[b*512+tid];
    #pragma unroll
    for(int p=0;p<8;p++) acc += qpart[((long)p<<15) + b*512 + tid];
    q_sh[tid] = acc;
    wv_sh[tid] = Wv[tid]; wc_sh[tid] = Wcov[tid];
    if(tid<100){ covL[tid]=cov[b*400+c0+tid]; padL[tid]=padm[b*400+c0+tid]; }
  }
  __syncthreads();
  // energy + exp: wave-per-row
  float wsum = 0.f;
  int i = w;
  u4 pf = {0,0,0,0};
  if(i<100) pf = ntld(pre + (((long)(b*400+c0+i))<<9) + lane*8);
  while(i<100){
    u4 cur = pf;
    int nx = i+8;
    if(nx<100) pf = ntld(pre + (((long)(b*400+c0+nx))<<9) + lane*8);
    float cv = covL[i];
    float part = 0.f;
    int a0 = lane*8;
    #pragma unroll
    for(int q4=0;q4<4;q4++){
      unsigned uu = (q4==0)?cur.x:(q4==1)?cur.y:(q4==2)?cur.z:cur.w;
      int a = a0 + q4*2;
      part += wv_sh[a]  * tanhf_(bf2f((unsigned short)(uu&0xffffu)) + q_sh[a]   + cv*wc_sh[a]);
      part += wv_sh[a+1]* tanhf_(bf2f((unsigned short)(uu>>16))    + q_sh[a+1] + cv*wc_sh[a+1]);
    }
    #pragma unroll
    for(int off=32;off;off>>=1) part += __shfl_xor(part, off, 64);
    if(lane==0){
      float e = (padL[i]>0.5f) ? -1e18f : part;
      float p = __expf(e);
      pL[i] = p;
      P_exp[b*400+c0+i] = p;
      wsum += p;
    }
    i = nx;
  }
  if(lane==0) red2[w]=wsum;
  __syncthreads();
  if(tid==0)
    S_part[b*4+cq] = red2[0]+red2[1]+red2[2]+red2[3]+red2[4]+red2[5]+red2[6]+red2[7];
  // context partial (unnormalized)
  float acc8[8];
  #pragma unroll
  for(int j=0;j<8;j++) acc8[j]=0.f;
  i = w;
  u4 cf = {0,0,0,0};
  if(i<100) cf = ntld(ctxbf + (((long)(b*400+c0+i))<<9) + lane*8);
  while(i<100){
    u4 cur = cf;
    int nx = i+8;
    if(nx<100) cf = ntld(ctxbf + (((long)(b*400+c0+nx))<<9) + lane*8);
    float pv = pL[i];
    acc8[0] = fmaf(pv, bf2f((unsigned short)(cur.x&0xffffu)), acc8[0]);
    acc8[1] = fmaf(pv, bf2f((unsigned short)(cur.x>>16)),     acc8[1]);
    acc8[2] = fmaf(pv, bf2f((unsigned short)(cur.y&0xffffu)), acc8[2]);
    acc8[3] = fmaf(pv, bf2f((unsigned short)(cur.y>>16)),     acc8[3]);
    acc8[4] = fmaf(pv, bf2f((unsigned short)(cur.z&0xffffu)), acc8[4]);
    acc8[5] = fmaf(pv, bf2f((unsigned short)(cur.z>>16)),     acc8[5]);
    acc8[6] = fmaf(pv, bf2f((unsigned short)(cur.w&0xffffu)), acc8[6]);
    acc8[7] = fmaf(pv, bf2f((unsigned short)(cur.w>>16)),     acc8[7]);
    i = nx;
  }
  f4 v0 = {acc8[0],acc8[1],acc8[2],acc8[3]};
  f4 v1 = {acc8[4],acc8[5],acc8[6],acc8[7]};
  *(f4*)(&pb[w][lane*8])   = v0;
  *(f4*)(&pb[w][lane*8+4]) = v1;
  __syncthreads();
  {
    float v = pb[0][tid]+pb[1][tid]+pb[2][tid]+pb[3][tid]
             +pb[4][tid]+pb[5][tid]+pb[6][tid]+pb[7][tid];
    ctxP[((long)b*4+cq)*512 + tid] = v;
  }
}

// ---------------- k_fin: finalize step 49 ----------------
__global__ __launch_bounds__(256) void k_fin(
  const float* __restrict__ ctxP, const float* __restrict__ S_part,
  const float* __restrict__ P_exp, const float* __restrict__ cov,
  unsigned short* __restrict__ ctxA, float* __restrict__ outp)
{
  __shared__ float red[256];
  int b = blockIdx.x; int tid = threadIdx.x;
  const int tb = T_STEPS-1;
  float S = S_part[b*4]+S_part[b*4+1]+S_part[b*4+2]+S_part[b*4+3];
  float inv = 1.f/S;
  float clp;
  {
    float p = P_exp[b*400+tid]; float attn = p*inv;
    float co = cov[b*400+tid];
    clp = fminf(attn, co);
    float nc = co+attn;
    outp[O_GATTN + (long)tb*25600 + b*400 + tid] = attn;
    outp[O_ATTN_LAST + b*400 + tid] = attn;
    outp[O_COVF + b*400 + tid] = nc;
  }
  if(tid<144){
    int i = 256+tid;
    float p = P_exp[b*400+i]; float attn = p*inv;
    float co = cov[b*400+i];
    clp += fminf(attn, co);
    float nc = co+attn;
    outp[O_GATTN + (long)tb*25600 + b*400 + i] = attn;
    outp[O_ATTN_LAST + b*400 + i] = attn;
    outp[O_COVF + b*400 + i] = nc;
  }
  red[tid]=clp; __syncthreads();
  for(int o=128;o;o>>=1){ if(tid<o) red[tid]+=red[tid+o]; __syncthreads(); }
  if(tid==0) outp[O_COVL + tb*64 + b] = red[0];
  for(int c=tid;c<512;c+=256){
    float v = (ctxP[(long)b*2048+c]+ctxP[(long)b*2048+512+c]
              +ctxP[(long)b*2048+1024+c]+ctxP[(long)b*2048+1536+c])*inv;
    outp[O_CTXF + b*512 + c] = v;
    ctxA[(long)(tb*64+b)*512 + c] = f2bf(v);
  }
}

// ---------------- fused post: pgen + maxout ----------------
__global__ __launch_bounds__(256) void k_post(
  const unsigned short* __restrict__ embU, const unsigned short* __restrict__ h0bf,
  const unsigned short* __restrict__ ctxA, const float* __restrict__ Wpg,
  const float* __restrict__ bpg, const float* __restrict__ RO,
  const float* __restrict__ ro_g, float* __restrict__ outp)
{
  int blk = blockIdx.x;
  if(blk < 800){
    int wid = threadIdx.x>>6, lane=threadIdx.x&63;
    int m = blk*4 + wid;
    float acc=0.f;
    #pragma unroll
    for(int i=0;i<8;i++){
      int k = i*64+lane;
      acc = fmaf(bf2f(ctxA[(long)m*512+k]), Wpg[k], acc);
      acc = fmaf(bf2f(h0bf[(long)m*512+k]), Wpg[512+k], acc);
      acc = fmaf(bf2f(embU[(long)m*512+k]), Wpg[1024+k], acc);
    }
    #pragma unroll
    for(int off=32; off; off>>=1) acc += __shfl_xor(acc, off, 64);
    if(lane==0) outp[O_PG + m] = sigmoidf_(acc + bpg[0]);
  } else {
    int o = (blk-800)*256 + threadIdx.x;
    int h = o & 255; int m = o>>8; int b = m & 63;
    float v0 = RO[(long)m*512 + 2*h]   + ro_g[b*512 + 2*h];
    float v1 = RO[(long)m*512 + 2*h+1] + ro_g[b*512 + 2*h+1];
    outp[O_GOUT + o] = fmaxf(v0,v1);
  }
}

extern "C" void kernel_launch(void* const* d_in, const int* in_sizes, int n_in,
                              void* d_out, int out_size, void* d_ws, size_t ws_size,
                              hipStream_t stream)
{
  (void)in_sizes; (void)n_in; (void)out_size; (void)ws_size;
  const int*   y       = (const int*)d_in[0];
  const float* hidden  = (const float*)d_in[1];
  const float* context = (const float*)d_in[2];
  const float* padm    = (const float*)d_in[3];
  const float* init_att= (const float*)d_in[4];
  const float* coverage= (const float*)d_in[5];
  const float* gctx    = (const float*)d_in[6];
  const float* embW    = (const float*)d_in[7];
  const float* W_ih    = (const float*)d_in[8];
  const float* W_hh    = (const float*)d_in[9];
  const float* b_ih    = (const float*)d_in[10];
  const float* b_hh    = (const float*)d_in[11];
  const float* W_pre   = (const float*)d_in[12];
  const float* b_pre   = (const float*)d_in[13];
  const float* W_q     = (const float*)d_in[14];
  const float* W_v     = (const float*)d_in[15];
  const float* W_cov   = (const float*)d_in[16];
  const float* W_pg    = (const float*)d_in[17];
  const float* b_pg    = (const float*)d_in[18];
  const float* W_ro    = (const float*)d_in[19];
  const float* b_ro    = (const float*)d_in[20];
  float* out = (float*)d_out;

  char* wsb = (char*)d_ws;
  size_t off = 0;
  auto alloc = [&](size_t bytes)->char*{ char* p = wsb+off; off += (bytes+255)&~255UL; return p; };
  unsigned short* pre    = (unsigned short*)alloc(25600UL*512*2);
  unsigned short* ctxbf  = (unsigned short*)alloc(13107200UL*2);
  unsigned short* embU   = (unsigned short*)alloc(3200UL*512*2);
  unsigned short* wihbf  = (unsigned short*)alloc(1536UL*512*2);
  unsigned short* wpreT  = (unsigned short*)alloc(512UL*512*2);
  unsigned short* wroT   = (unsigned short*)alloc(512UL*2048*2);
  unsigned short* Wgru   = (unsigned short*)alloc(192UL*8192*2);
  unsigned short* WqP    = (unsigned short*)alloc(262144UL*2);
  float* gi_emb = (float*)alloc(3200UL*1536*4);
  float* RO     = (float*)alloc(3200UL*512*4);
  float* q_g    = (float*)alloc(64UL*512*4);
  float* ro_g   = (float*)alloc(64UL*512*4);
  float* hrow0  = (float*)alloc(64UL*512*4);
  float* hrow1  = (float*)alloc(64UL*512*4);
  float* gctxT  = (float*)alloc(512UL*64*4);
  unsigned short* h0bf = (unsigned short*)alloc(3200UL*512*2);
  unsigned short* h0bf_init = (unsigned short*)alloc(64UL*512*2);
  unsigned short* ctx0bf    = (unsigned short*)alloc(64UL*512*2);
  unsigned short* ctxA = (unsigned short*)alloc(3200UL*512*2);
  float* ctxP   = (float*)alloc(64UL*4*512*4);
  float* P_exp  = (float*)alloc(64UL*400*4);
  float* S_part = (float*)alloc(64UL*4*4);
  float* qpart  = (float*)alloc(8UL*64*512*4);
  float* cov    = (float*)alloc(64UL*400*4);

  // converts + init (3 slots)
  conv_ctx <<<dim3(51200),dim3(256),0,stream>>>(context, ctxbf);
  conv_emb <<<dim3(6400), dim3(256),0,stream>>>(y, embW, embU);
  conv_rest<<<dim3(15844),dim3(256),0,stream>>>(W_ih, W_hh, W_pre, W_ro, W_q,
                                                hidden, init_att, gctx, coverage,
                                                wihbf, wpreT, wroT, Wgru, WqP,
                                                hrow0, h0bf_init, ctx0bf, gctxT, cov);

  // precompute GEMMs (3 slots)
  mfma_gemm<1><<<dim3(200,4),dim3(256),0,stream>>>(ctxbf,512, wpreT,512,  pre,   512, b_pre, 512);
  mfma_gemm<0><<<dim3(25,12),dim3(256),0,stream>>>(embU, 512, wihbf,512,  gi_emb,1536, b_ih, 512);
  small2<<<dim3(256),dim3(256),0,stream>>>(gctxT, W_q, W_ro, q_g, ro_g);

  // scan: 2 kernels/step
  for(int t=0; t<T_STEPS; t++){
    float* hin  = (t&1) ? hrow1 : hrow0;
    float* hout = (t&1) ? hrow0 : hrow1;
    const unsigned short* hprevbf = t ? (h0bf + (long)(t-1)*32768) : h0bf_init;
    k_gru3<<<dim3(72),dim3(256),0,stream>>>(ctx0bf, ctxP, S_part, P_exp, hprevbf,
                                            hin, hout, Wgru, WqP, gi_emb, b_hh,
                                            h0bf, qpart, cov, ctxA, out, t);
    k_energy2<<<dim3(4,64),dim3(512),0,stream>>>(pre, qpart, q_g, cov, W_v, W_cov,
                                                 padm, ctxbf, P_exp, S_part, ctxP);
  }

  // post (3 slots)
  k_fin<<<dim3(64),dim3(256),0,stream>>>(ctxP, S_part, P_exp, cov, ctxA, out);
  mfma_gemm_ro<<<dim3(25,4),dim3(256),0,stream>>>(embU, h0bf, ctxA, wroT, RO, b_ro);
  k_post<<<dim3(4000),dim3(256),0,stream>>>(embU, h0bf, ctxA, W_pg, b_pg, RO, ro_g, out);
}